// Round 6
// baseline (735.949 us; speedup 1.0000x reference)
//
#include <hip/hip_runtime.h>
#include <hip/hip_bf16.h>

#define N_NODES  50000
#define N_EDGES  400000
#define E_TOT    450000   // edges + self loops
#define N_GRAPHS 128
#define D_IN     768
#define D_HID    256

typedef __hip_bfloat16 bf16;
typedef __attribute__((ext_vector_type(8))) short short8;
typedef __attribute__((ext_vector_type(4))) short short4v;
typedef __attribute__((ext_vector_type(4))) float f32x4;

__device__ __forceinline__ float b2f(bf16 v) { return __bfloat162float(v); }
__device__ __forceinline__ float us2f(unsigned short u) { return __uint_as_float((unsigned)u << 16); }
__device__ __forceinline__ int clampN(int v) { return min(max(v, 0), N_NODES - 1); }
// fp32 -> bf16 bits (RNE), as short for MFMA fragments
__device__ __forceinline__ short f2bs(float f) {
  unsigned u = __float_as_uint(f);
  return (short)((u + 0x7FFFu + ((u >> 16) & 1u)) >> 16);
}

// async global->LDS, 16B per lane. LDS dest is wave-uniform base + lane*16.
__device__ __forceinline__ void gload_lds16(const void* g, void* l) {
  __builtin_amdgcn_global_load_lds(
      (const __attribute__((address_space(1))) void*)g,
      (__attribute__((address_space(3))) void*)l, 16, 0, 0);
}

__device__ __forceinline__ float waveReduceSum(float v) {
#pragma unroll
  for (int o = 32; o > 0; o >>= 1) v += __shfl_down(v, o);
  return v;
}

__device__ __forceinline__ float blockReduce256(float v, volatile float* buf4) {
  int lane = threadIdx.x & 63, wid = threadIdx.x >> 6;
  v = waveReduceSum(v);
  if (lane == 0) buf4[wid] = v;
  __syncthreads();
  float s = buf4[0] + buf4[1] + buf4[2] + buf4[3];
  __syncthreads();
  return s;
}

// ---------------- index dtype detection (zeroes its own flag; single block) ----------------
__global__ __launch_bounds__(256) void detect_idx_kernel(
    const int* __restrict__ edge32, int* __restrict__ flagNZ) {
  if (threadIdx.x == 0) *flagNZ = 0;
  __syncthreads();
  int t = threadIdx.x;
  int nz = 0;
#pragma unroll
  for (int i = 0; i < 4; ++i) {
    int idx = 2 * (t + i * 256) + 1;
    if (edge32[idx] != 0) nz = 1;
  }
  if (nz) atomicOr(flagNZ, 1);
}

// normalize indices; zeroes deg[]; also does both weight transposes (fused)
__global__ __launch_bounds__(256) void normalize_idx_kernel(
    const void* __restrict__ edge, const void* __restrict__ nbin,
    const int* __restrict__ flagNZ,
    int* __restrict__ src32, int* __restrict__ dst32, int* __restrict__ nb32,
    int* __restrict__ deg,
    const float* __restrict__ W1, const float* __restrict__ W2,
    short* __restrict__ W1T, short* __restrict__ W2T) {
  bool is64 = (*flagNZ == 0);
  long i = (long)blockIdx.x * 256 + threadIdx.x;
  const int*       e32 = (const int*)edge;
  const long long* e64 = (const long long*)edge;
  const int*       n32 = (const int*)nbin;
  const long long* n64 = (const long long*)nbin;
  if (i < N_NODES) deg[i] = 0;
  if (i < N_EDGES) {
    src32[i] = clampN(is64 ? (int)e64[i] : e32[i]);
    dst32[i] = clampN(is64 ? (int)e64[N_EDGES + i] : e32[N_EDGES + i]);
  }
  long j = i - N_EDGES;
  if (j >= 0 && j < N_NODES)
    nb32[j] = min(max(is64 ? (int)n64[j] : n32[j], 0), N_GRAPHS - 1);
  // fused weight transpose + bf16 convert
  int t = (int)i;
  if (t < D_IN * D_HID) {
    int n = t / D_IN, k = t - n * D_IN;
    W1T[t] = f2bs(W1[(size_t)k * D_HID + n]);
  }
  int j2 = t - D_IN * D_HID;
  if (j2 >= 0 && j2 < D_HID * D_HID) {
    int n = j2 / D_HID, k = j2 - n * D_HID;
    W2T[j2] = f2bs(W2[(size_t)k * D_HID + n]);
  }
}

// ---------------- CSR build: histogram -> hierarchical scan -> scatter ----------------
__global__ __launch_bounds__(256) void hist_kernel(
    const int* __restrict__ dst, int* __restrict__ deg) {
  int i = blockIdx.x * 256 + threadIdx.x;
  if (i >= E_TOT) return;
  int d = (i < N_EDGES) ? dst[i] : (i - N_EDGES);
  atomicAdd(&deg[d], 1);
}

#define SCAN_VPT 4
#define SCAN_BLK (256 * SCAN_VPT)
#define SCAN_NB  ((N_NODES + SCAN_BLK - 1) / SCAN_BLK)  // 49

__global__ __launch_bounds__(256) void scan_local_kernel(
    const int* __restrict__ deg, int* __restrict__ incl, int* __restrict__ blockSums) {
  __shared__ int wsum[4];
  int lane = threadIdx.x & 63, wid = threadIdx.x >> 6;
  int tbase = blockIdx.x * SCAN_BLK + threadIdx.x * SCAN_VPT;
  int v[SCAN_VPT];
  int s = 0;
#pragma unroll
  for (int j = 0; j < SCAN_VPT; ++j) {
    int i = tbase + j;
    v[j] = (i < N_NODES) ? deg[i] : 0;
    s += v[j];
  }
  int sc = s;
#pragma unroll
  for (int o = 1; o < 64; o <<= 1) {
    int t = __shfl_up(sc, o);
    if (lane >= o) sc += t;
  }
  if (lane == 63) wsum[wid] = sc;
  __syncthreads();
  int woff = 0;
  for (int w = 0; w < wid; ++w) woff += wsum[w];
  int run = woff + sc - s;
#pragma unroll
  for (int j = 0; j < SCAN_VPT; ++j) {
    run += v[j];
    int i = tbase + j;
    if (i < N_NODES) incl[i] = run;
  }
  if (threadIdx.x == 255)
    blockSums[blockIdx.x] = woff + sc;
}

// scan_add with spine folded in: each block computes its scan-block offset by
// wave-reducing the 49 raw block sums (SCAN_NB <= 64).
__global__ __launch_bounds__(256) void scan_add_kernel(
    const int* __restrict__ deg, const int* __restrict__ incl,
    const int* __restrict__ bsums,
    int* __restrict__ rowptr, int* __restrict__ pos) {
  __shared__ int offSh;
  int sb = blockIdx.x >> 2;   // 256-node block -> 1024-node scan block
  if (threadIdx.x < 64) {
    int v = (threadIdx.x < sb) ? bsums[threadIdx.x] : 0;
#pragma unroll
    for (int o = 32; o > 0; o >>= 1) v += __shfl_down(v, o);
    if (threadIdx.x == 0) offSh = v;
  }
  __syncthreads();
  int i = blockIdx.x * 256 + threadIdx.x;
  if (i >= N_NODES) return;
  int ic = incl[i] + offSh;
  rowptr[i + 1] = ic;
  pos[i] = ic - deg[i];
  if (i == 0) rowptr[0] = 0;
}

__global__ __launch_bounds__(256) void scatter_kernel(
    const int* __restrict__ src, const int* __restrict__ dst,
    int* __restrict__ pos, int* __restrict__ srcS) {
  int i = blockIdx.x * 256 + threadIdx.x;
  if (i >= E_TOT) return;
  int s, d;
  if (i < N_EDGES) { s = src[i]; d = dst[i]; } else { s = d = i - N_EDGES; }
  int j = atomicAdd(&pos[d], 1);
  srcS[j] = s;
}

// ---------------- fused relevance + bf16 convert: ONE WAVE PER NODE ----------------
__global__ __launch_bounds__(256) void rel_conv_kernel(
    const float* __restrict__ x, const float* __restrict__ claim,
    const int* __restrict__ nb, short* __restrict__ Abf,
    float* __restrict__ alphas, float* __restrict__ alphad,
    float* __restrict__ bnsums, float* __restrict__ bnsq) {
  int wid = threadIdx.x >> 6, lane = threadIdx.x & 63;
  int n = blockIdx.x * 4 + wid;     // N_NODES % 4 == 0
  if (blockIdx.x == 0) { bnsums[threadIdx.x] = 0.f; bnsq[threadIdx.x] = 0.f; }
  if (n >= N_NODES) return;
  if (lane == 0) { alphas[n] = 0.f; alphad[n] = 0.f; }
  int g = nb[n];
  const f32x4* xr = (const f32x4*)(x + (size_t)n * D_IN);
  const f32x4* cr = (const f32x4*)(claim + (size_t)g * D_IN);
  f32x4 xv[3];
  float dot = 0.f, nx = 0.f, nc = 0.f;
#pragma unroll
  for (int j = 0; j < 3; ++j) {
    xv[j] = xr[lane + j * 64];
    f32x4 cv = cr[lane + j * 64];
#pragma unroll
    for (int k = 0; k < 4; ++k) {
      dot += xv[j][k] * cv[k];
      nx  += xv[j][k] * xv[j][k];
      nc  += cv[k] * cv[k];
    }
  }
#pragma unroll
  for (int o = 32; o > 0; o >>= 1) {
    dot += __shfl_xor(dot, o);
    nx  += __shfl_xor(nx, o);
    nc  += __shfl_xor(nc, o);
  }
  float rel = dot / fmaxf(sqrtf(nx) * sqrtf(nc), 1e-8f);
  short4v* ab = (short4v*)(Abf + (size_t)n * D_IN);
#pragma unroll
  for (int j = 0; j < 3; ++j) {
    short4v o4;
#pragma unroll
    for (int k = 0; k < 4; ++k) o4[k] = f2bs(xv[j][k] * rel);
    ab[lane + j * 64] = o4;
  }
}

// ---------------- BN finalize+scale/shift+ReLU+bf16 (layer-2 A); zeroes alpha + pooled ----------------
__global__ __launch_bounds__(256) void bn_conv_kernel(
    const float* __restrict__ agg, const float* __restrict__ sums,
    const float* __restrict__ sumsq, const float* __restrict__ gamma,
    const float* __restrict__ beta, short* __restrict__ A2,
    float* __restrict__ alphas, float* __restrict__ alphad,
    float* __restrict__ pooled) {
  int i = blockIdx.x * 256 + threadIdx.x;   // vec-4 index
  if ((i & 63) == 0) { int n = i >> 6; alphas[n] = 0.f; alphad[n] = 0.f; }
  if (i < N_GRAPHS * D_HID) pooled[i] = 0.f;
  f32x4 v = ((const f32x4*)agg)[i];
  int col = (i << 2) & (D_HID - 1);
  short4v o;
#pragma unroll
  for (int j = 0; j < 4; ++j) {
    float mu  = sums[col + j] * (1.f / N_NODES);
    float var = fmaxf(sumsq[col + j] * (1.f / N_NODES) - mu * mu, 0.f);
    float sc  = gamma[col + j] * rsqrtf(var + 1e-5f);
    float sh  = beta[col + j] - mu * sc;
    float t = fmaxf(v[j] * sc + sh, 0.f);
    o[j] = f2bs(t);
  }
  ((short4v*)A2)[i] = o;
}

// ---------------- MFMA GEMM (bf16 in/out): C[M,256] = A[M,K] @ B[K,256] ----------------
// 128x128 tile per block, 4 waves (2x2), per-wave 64x64 = 4x4 MFMA tiles, BK=32.
// LDS fragment-major layout (R4-verified): staging decode quad-fastest so each
// 4-lane group fetches a contiguous 64B row chunk (coalesced); ds_read offsets
// l16*32+quadL*8. (R5's quad-major remap scattered the staging sources 64-ways
// and regressed -- reverted.)
// XCD PAIRING SWIZZLE: the two n-halves of each m-tile share A rows. Hardware
// round-robins blockIdx across 8 XCDs, so map pair p, half q -> hw bid
// (p/8)*16 + q*8 + p%8: both halves land on the SAME XCD => second A read is
// an L2 hit instead of a second HBM fetch.
// Fused epilogue: alpha_s/alpha_d = acc . a (cross-lane reduce + atomicAdd), C bf16.
#define GEMM_BK 32
__global__ __launch_bounds__(256) void mfma_gemm_bf16_kernel(
    const short* __restrict__ Abf, const short* __restrict__ BT,
    const float* __restrict__ aS, const float* __restrict__ aD,
    float* __restrict__ alphaS, float* __restrict__ alphaD,
    bf16* __restrict__ C, int M, int K) {
  __shared__ short As[4096];   // 8 m-tiles * 512 shorts
  __shared__ short Bs[4096];   // 8 n-tiles * 512 shorts
  int tid = threadIdx.x;
  int wave = tid >> 6, lane = tid & 63;
  int l16 = lane & 15, quadL = lane >> 4;
  int wr = wave >> 1, wc = wave & 1;
  // XCD pairing decode
  int B = blockIdx.x;
  int p = (B >> 4) * 8 + (B & 7);      // m-tile index
  int q = (B >> 3) & 1;                // n-half
  int mTiles = (M + 127) >> 7;
  if (p >= mTiles) return;
  int mBase = p * 128;
  int nBase = q * 128;

  const short* gA[2];
  const short* gB[2];
  int ldsOff[2];
#pragma unroll
  for (int r = 0; r < 2; ++r) {
    int slot = r * 256 + tid;              // 16B granule index 0..511 (linear dest)
    int mt = slot >> 6, m16 = (slot >> 2) & 15, quad = slot & 3;  // quad fastest: coalesced
    int rowA = min(mBase + mt * 16 + m16, M - 1);   // clamp OOB rows (outputs masked)
    gA[r] = Abf + (size_t)rowA * K + quad * 8;
    gB[r] = BT + (size_t)(nBase + mt * 16 + m16) * K + quad * 8;
    ldsOff[r] = (r * 256 + wave * 64) * 8; // wave-uniform LDS base (shorts)
  }
  int aOff[4], bOff[4];
#pragma unroll
  for (int i = 0; i < 4; ++i) {
    aOff[i] = (wr * 4 + i) * 512 + l16 * 32 + quadL * 8;
    bOff[i] = (wc * 4 + i) * 512 + l16 * 32 + quadL * 8;
  }

  f32x4 acc[4][4] = {};

  for (int k0 = 0; k0 < K; k0 += GEMM_BK) {
#pragma unroll
    for (int r = 0; r < 2; ++r) {
      gload_lds16(gA[r] + k0, As + ldsOff[r]);
      gload_lds16(gB[r] + k0, Bs + ldsOff[r]);
    }
    __syncthreads();   // drains vmcnt before barrier
    short8 af[4], bfv[4];
#pragma unroll
    for (int i = 0; i < 4; ++i) af[i] = *(const short8*)(As + aOff[i]);
#pragma unroll
    for (int j = 0; j < 4; ++j) bfv[j] = *(const short8*)(Bs + bOff[j]);
#pragma unroll
    for (int i = 0; i < 4; ++i)
#pragma unroll
      for (int j = 0; j < 4; ++j)
        acc[i][j] = __builtin_amdgcn_mfma_f32_16x16x32_bf16(af[i], bfv[j], acc[i][j], 0, 0, 0);
    __syncthreads();
  }

  // ---- epilogue: fused alpha + bf16 store ----
  float asv[4], adv[4];
#pragma unroll
  for (int j = 0; j < 4; ++j) {
    int col = nBase + (wc * 4 + j) * 16 + l16;
    asv[j] = aS[col]; adv[j] = aD[col];
  }
#pragma unroll
  for (int i = 0; i < 4; ++i) {
    int m0 = mBase + (wr * 4 + i) * 16 + quadL * 4;
#pragma unroll
    for (int r = 0; r < 4; ++r) {
      int m = m0 + r;
      float ss = acc[i][0][r] * asv[0] + acc[i][1][r] * asv[1] +
                 acc[i][2][r] * asv[2] + acc[i][3][r] * asv[3];
      float dd = acc[i][0][r] * adv[0] + acc[i][1][r] * adv[1] +
                 acc[i][2][r] * adv[2] + acc[i][3][r] * adv[3];
#pragma unroll
      for (int o = 1; o < 16; o <<= 1) {
        ss += __shfl_xor(ss, o);
        dd += __shfl_xor(dd, o);
      }
      if (m < M) {
        if (l16 == 0) { atomicAdd(&alphaS[m], ss); atomicAdd(&alphaD[m], dd); }
#pragma unroll
        for (int j = 0; j < 4; ++j)
          C[(size_t)m * D_HID + nBase + (wc * 4 + j) * 16 + l16] =
              __float2bfloat16(acc[i][j][r]);
      }
    }
  }
}

// ---------------- fused GAT softmax + aggregate: one wave per dst node ----------------
// Single gather pass; chunk-0 edges cached in registers, exp weight shfl'd.
// FUSE_POOL=1 (layer 2): skip agg write, apply relu(row+b2) and atomicAdd into
// pooled[graph] directly (saves 51.2MB write + 51.2MB read + a dispatch).
template <int FUSE_POOL>
__global__ __launch_bounds__(256) void gat_agg_kernel(
    const int* __restrict__ rowptr, const int* __restrict__ srcS,
    const float* __restrict__ as_, const float* __restrict__ ad_,
    const bf16* __restrict__ h, float* __restrict__ agg,
    const int* __restrict__ nb, const float* __restrict__ bias2,
    float* __restrict__ pooled) {
  int wid = threadIdx.x >> 6, lane = threadIdx.x & 63;
  int n = blockIdx.x * 4 + wid;
  if (n >= N_NODES) return;
  int start = rowptr[n], end = rowptr[n + 1];
  int deg = end - start;
  float adn = ad_[n];
  // cache chunk 0 in registers
  int sidx = 0;
  float e0 = -1e30f;
  if (lane < deg) {
    sidx = srcS[start + lane];
    float e = as_[sidx] + adn;
    e0 = e > 0.f ? e : 0.2f * e;
  }
  float m = e0;
  for (int j0 = start + 64; j0 < end; j0 += 64) {   // rare (deg > 64)
    int j = j0 + lane;
    if (j < end) {
      float e = as_[srcS[j]] + adn;
      e = e > 0.f ? e : 0.2f * e;
      m = fmaxf(m, e);
    }
  }
#pragma unroll
  for (int o = 32; o > 0; o >>= 1) m = fmaxf(m, __shfl_xor(m, o));
  float pw = (lane < deg) ? __expf(e0 - m) : 0.f;   // per-lane weight, shfl'd later
  float ssum = pw;
  for (int j0 = start + 64; j0 < end; j0 += 64) {
    int j = j0 + lane;
    if (j < end) {
      float e = as_[srcS[j]] + adn;
      e = e > 0.f ? e : 0.2f * e;
      ssum += __expf(e - m);
    }
  }
#pragma unroll
  for (int o = 32; o > 0; o >>= 1) ssum += __shfl_xor(ssum, o);
  float a0 = 0.f, a1 = 0.f, a2 = 0.f, a3 = 0.f;
  const unsigned short* hp = (const unsigned short*)h;
  int c0 = min(deg, 64);
  for (int t = 0; t < c0; ++t) {
    int s = __shfl(sidx, t);
    float w = __shfl(pw, t);
    const ushort4 hv = *(const ushort4*)(hp + (size_t)s * D_HID + lane * 4);
    a0 += us2f(hv.x) * w;
    a1 += us2f(hv.y) * w;
    a2 += us2f(hv.z) * w;
    a3 += us2f(hv.w) * w;
  }
  for (int j = start + 64; j < end; ++j) {   // rare tail
    int s = srcS[j];
    float e = as_[s] + adn;
    e = e > 0.f ? e : 0.2f * e;
    float w = __expf(e - m);
    const ushort4 hv = *(const ushort4*)(hp + (size_t)s * D_HID + lane * 4);
    a0 += us2f(hv.x) * w;
    a1 += us2f(hv.y) * w;
    a2 += us2f(hv.z) * w;
    a3 += us2f(hv.w) * w;
  }
  float inv = 1.f / ssum;
  if (FUSE_POOL) {
    int g = nb[n];
    const float* bb = bias2 + lane * 4;
    float* pg = pooled + (size_t)g * D_HID + lane * 4;
    atomicAdd(pg + 0, fmaxf(a0 * inv + bb[0], 0.f));
    atomicAdd(pg + 1, fmaxf(a1 * inv + bb[1], 0.f));
    atomicAdd(pg + 2, fmaxf(a2 * inv + bb[2], 0.f));
    atomicAdd(pg + 3, fmaxf(a3 * inv + bb[3], 0.f));
  } else {
    float4 o4 = {a0 * inv, a1 * inv, a2 * inv, a3 * inv};
    *(float4*)(agg + (size_t)n * D_HID + lane * 4) = o4;
  }
}

// ---------------- batch norm stats (accumulators pre-zeroed by rel_conv) ----------------
__global__ __launch_bounds__(256) void bn_stats_kernel(
    const float* __restrict__ h, float* __restrict__ sums, float* __restrict__ sumsq) {
  int col = threadIdx.x;
  float s = 0.f, q = 0.f;
  for (int r = blockIdx.x; r < N_NODES; r += gridDim.x) {
    float v = h[(size_t)r * D_HID + col];
    s += v; q += v * v;
  }
  atomicAdd(&sums[col], s);
  atomicAdd(&sumsq[col], q);
}

// ---------------- classifier; per-graph count via binary search on sorted nb ----------------
__global__ __launch_bounds__(256) void clf_kernel(
    const float* __restrict__ pooled, const int* __restrict__ nb,
    const float* __restrict__ claim, const float* __restrict__ clfW,
    const float* __restrict__ clfb, float* __restrict__ out) {
  __shared__ float buf[4];
  __shared__ int cntSh;
  int g = blockIdx.x;
  if (threadIdx.x == 0) {
    int lo = 0, hi = N_NODES;
    while (lo < hi) { int mid = (lo + hi) >> 1; if (nb[mid] < g) lo = mid + 1; else hi = mid; }
    int lb = lo; hi = N_NODES;
    while (lo < hi) { int mid = (lo + hi) >> 1; if (nb[mid] <= g) lo = mid + 1; else hi = mid; }
    cntSh = lo - lb;
  }
  __syncthreads();
  float inv = 1.f / fmaxf((float)cntSh, 1.f);
  float p = 0.f;
  for (int d = threadIdx.x; d < (D_HID + D_IN); d += 256) {
    float w = clfW[d];
    float v = (d < D_HID) ? pooled[(size_t)g * D_HID + d] * inv
                          : claim[(size_t)g * D_IN + (d - D_HID)];
    p += v * w;
  }
  p = blockReduce256(p, buf);
  if (threadIdx.x == 0) out[g] = p + clfb[0];
}

extern "C" void kernel_launch(void* const* d_in, const int* in_sizes, int n_in,
                              void* d_out, int out_size, void* d_ws, size_t ws_size,
                              hipStream_t stream) {
  const float* claim = (const float*)d_in[0];
  const float* x     = (const float*)d_in[1];
  const void*  edge  = d_in[2];
  const void*  nbin  = d_in[3];
  const float* W1    = (const float*)d_in[4];
  const float* as1   = (const float*)d_in[5];
  const float* ad1   = (const float*)d_in[6];
  // d_in[7] = b1: cancels in BatchNorm
  const float* W2    = (const float*)d_in[8];
  const float* as2   = (const float*)d_in[9];
  const float* ad2   = (const float*)d_in[10];
  const float* b2v   = (const float*)d_in[11];
  const float* gamma = (const float*)d_in[12];
  const float* beta  = (const float*)d_in[13];
  const float* clfW  = (const float*)d_in[14];
  const float* clfb  = (const float*)d_in[15];
  float* out = (float*)d_out;

  char* wsb = (char*)d_ws;
  size_t off = 0;
  auto alloc = [&](size_t bytes) -> char* {
    char* p = wsb + off;
    off = (off + bytes + 255) & ~(size_t)255;
    return p;
  };
  int*   flagNZ = (int*)alloc(sizeof(int));
  int*   src32  = (int*)alloc((size_t)N_EDGES * sizeof(int));
  int*   dst32  = (int*)alloc((size_t)N_EDGES * sizeof(int));
  int*   nb32   = (int*)alloc((size_t)N_NODES * sizeof(int));
  int*   deg    = (int*)alloc((size_t)N_NODES * sizeof(int));
  int*   rowptr = (int*)alloc((size_t)(N_NODES + 1) * sizeof(int));
  int*   pos    = (int*)alloc((size_t)N_NODES * sizeof(int));
  int*   incl   = (int*)alloc((size_t)N_NODES * sizeof(int));
  int*   bsums  = (int*)alloc((size_t)SCAN_NB * sizeof(int));
  int*   srcS   = (int*)alloc((size_t)E_TOT * sizeof(int));
  short* W1T    = (short*)alloc((size_t)D_IN * D_HID * sizeof(short));
  short* W2T    = (short*)alloc((size_t)D_HID * D_HID * sizeof(short));
  float* alphas = (float*)alloc((size_t)N_NODES * sizeof(float));
  float* alphad = (float*)alloc((size_t)N_NODES * sizeof(float));
  float* bnsums = (float*)alloc(D_HID * sizeof(float));
  float* bnsq   = (float*)alloc(D_HID * sizeof(float));
  float* pooled = (float*)alloc((size_t)N_GRAPHS * D_HID * sizeof(float));
  float* agg    = (float*)alloc((size_t)N_NODES * D_HID * sizeof(float));
  bf16*  h      = (bf16*) alloc((size_t)N_NODES * D_HID * sizeof(bf16));
  short* Abf    = (short*)alloc((size_t)N_NODES * D_IN * sizeof(short));
  short* A2     = Abf;   // layer-2 bf16 A reuses Abf

  // ---- index normalization + CSR build (no memsets: kernels self-initialize) ----
  detect_idx_kernel<<<1, 256, 0, stream>>>((const int*)edge, flagNZ);
  normalize_idx_kernel<<<(N_EDGES + N_NODES + 255) / 256, 256, 0, stream>>>(
      edge, nbin, flagNZ, src32, dst32, nb32, deg, W1, W2, W1T, W2T);
  int egrid = (E_TOT + 255) / 256;
  hist_kernel<<<egrid, 256, 0, stream>>>(dst32, deg);
  scan_local_kernel<<<SCAN_NB, 256, 0, stream>>>(deg, incl, bsums);
  scan_add_kernel<<<(N_NODES + 255) / 256, 256, 0, stream>>>(deg, incl, bsums, rowptr, pos);
  scatter_kernel<<<egrid, 256, 0, stream>>>(src32, dst32, pos, srcS);

  // XCD-paired GEMM grid: ceil(mTiles/8)*16 hw blocks
  int mTiles = (N_NODES + 127) / 128;             // 391
  int gemmGrid = ((mTiles + 7) / 8) * 16;         // 784

  // ---- layer 1 ----
  rel_conv_kernel<<<N_NODES / 4, 256, 0, stream>>>(
      x, claim, nb32, Abf, alphas, alphad, bnsums, bnsq);
  mfma_gemm_bf16_kernel<<<gemmGrid, 256, 0, stream>>>(
      Abf, W1T, as1, ad1, alphas, alphad, h, N_NODES, D_IN);
  gat_agg_kernel<0><<<N_NODES / 4, 256, 0, stream>>>(
      rowptr, srcS, alphas, alphad, h, agg, nb32, b2v, pooled);

  bn_stats_kernel<<<256, 256, 0, stream>>>(agg, bnsums, bnsq);

  // ---- layer 2 (BN finalize + scale/shift + ReLU folded into bf16 conversion) ----
  bn_conv_kernel<<<(N_NODES * D_HID / 4 + 255) / 256, 256, 0, stream>>>(
      agg, bnsums, bnsq, gamma, beta, A2, alphas, alphad, pooled);
  mfma_gemm_bf16_kernel<<<gemmGrid, 256, 0, stream>>>(
      A2, W2T, as2, ad2, alphas, alphad, h, N_NODES, D_HID);
  gat_agg_kernel<1><<<N_NODES / 4, 256, 0, stream>>>(
      rowptr, srcS, alphas, alphad, h, agg, nb32, b2v, pooled);

  // ---- classifier (pool fused into gat_agg<1>) ----
  clf_kernel<<<N_GRAPHS, 256, 0, stream>>>(pooled, nb32, claim, clfW, clfb, out);
}

// Round 9
// 608.576 us; speedup vs baseline: 1.2093x; 1.2093x over previous
//
#include <hip/hip_runtime.h>
#include <hip/hip_bf16.h>

#define N_NODES  50000
#define N_EDGES  400000
#define E_TOT    450000   // edges + self loops
#define N_GRAPHS 128
#define D_IN     768
#define D_HID    256

typedef __hip_bfloat16 bf16;
typedef __attribute__((ext_vector_type(8))) short short8;
typedef __attribute__((ext_vector_type(4))) short short4v;
typedef __attribute__((ext_vector_type(4))) float f32x4;

__device__ __forceinline__ float b2f(bf16 v) { return __bfloat162float(v); }
__device__ __forceinline__ float us2f(unsigned short u) { return __uint_as_float((unsigned)u << 16); }
__device__ __forceinline__ int clampN(int v) { return min(max(v, 0), N_NODES - 1); }
// fp32 -> bf16 bits (RNE), as short for MFMA fragments
__device__ __forceinline__ short f2bs(float f) {
  unsigned u = __float_as_uint(f);
  return (short)((u + 0x7FFFu + ((u >> 16) & 1u)) >> 16);
}

// async global->LDS, 16B per lane. LDS dest is wave-uniform base + lane*16.
__device__ __forceinline__ void gload_lds16(const void* g, void* l) {
  __builtin_amdgcn_global_load_lds(
      (const __attribute__((address_space(1))) void*)g,
      (__attribute__((address_space(3))) void*)l, 16, 0, 0);
}

__device__ __forceinline__ float waveReduceSum(float v) {
#pragma unroll
  for (int o = 32; o > 0; o >>= 1) v += __shfl_down(v, o);
  return v;
}

__device__ __forceinline__ float blockReduce256(float v, volatile float* buf4) {
  int lane = threadIdx.x & 63, wid = threadIdx.x >> 6;
  v = waveReduceSum(v);
  if (lane == 0) buf4[wid] = v;
  __syncthreads();
  float s = buf4[0] + buf4[1] + buf4[2] + buf4[3];
  __syncthreads();
  return s;
}

// ---------------- index dtype detection (zeroes its own flag; single block) ----------------
__global__ __launch_bounds__(256) void detect_idx_kernel(
    const int* __restrict__ edge32, int* __restrict__ flagNZ) {
  if (threadIdx.x == 0) *flagNZ = 0;
  __syncthreads();
  int t = threadIdx.x;
  int nz = 0;
#pragma unroll
  for (int i = 0; i < 4; ++i) {
    int idx = 2 * (t + i * 256) + 1;
    if (edge32[idx] != 0) nz = 1;
  }
  if (nz) atomicOr(flagNZ, 1);
}

// normalize indices; zeroes deg[]; also does both weight transposes (fused)
__global__ __launch_bounds__(256) void normalize_idx_kernel(
    const void* __restrict__ edge, const void* __restrict__ nbin,
    const int* __restrict__ flagNZ,
    int* __restrict__ src32, int* __restrict__ dst32, int* __restrict__ nb32,
    int* __restrict__ deg,
    const float* __restrict__ W1, const float* __restrict__ W2,
    short* __restrict__ W1T, short* __restrict__ W2T) {
  bool is64 = (*flagNZ == 0);
  long i = (long)blockIdx.x * 256 + threadIdx.x;
  const int*       e32 = (const int*)edge;
  const long long* e64 = (const long long*)edge;
  const int*       n32 = (const int*)nbin;
  const long long* n64 = (const long long*)nbin;
  if (i < N_NODES) deg[i] = 0;
  if (i < N_EDGES) {
    src32[i] = clampN(is64 ? (int)e64[i] : e32[i]);
    dst32[i] = clampN(is64 ? (int)e64[N_EDGES + i] : e32[N_EDGES + i]);
  }
  long j = i - N_EDGES;
  if (j >= 0 && j < N_NODES)
    nb32[j] = min(max(is64 ? (int)n64[j] : n32[j], 0), N_GRAPHS - 1);
  // fused weight transpose + bf16 convert
  int t = (int)i;
  if (t < D_IN * D_HID) {
    int n = t / D_IN, k = t - n * D_IN;
    W1T[t] = f2bs(W1[(size_t)k * D_HID + n]);
  }
  int j2 = t - D_IN * D_HID;
  if (j2 >= 0 && j2 < D_HID * D_HID) {
    int n = j2 / D_HID, k = j2 - n * D_HID;
    W2T[j2] = f2bs(W2[(size_t)k * D_HID + n]);
  }
}

// ---------------- CSR build: histogram -> hierarchical scan -> scatter ----------------
__global__ __launch_bounds__(256) void hist_kernel(
    const int* __restrict__ dst, int* __restrict__ deg) {
  int i = blockIdx.x * 256 + threadIdx.x;
  if (i >= E_TOT) return;
  int d = (i < N_EDGES) ? dst[i] : (i - N_EDGES);
  atomicAdd(&deg[d], 1);
}

#define SCAN_VPT 4
#define SCAN_BLK (256 * SCAN_VPT)
#define SCAN_NB  ((N_NODES + SCAN_BLK - 1) / SCAN_BLK)  // 49

__global__ __launch_bounds__(256) void scan_local_kernel(
    const int* __restrict__ deg, int* __restrict__ incl, int* __restrict__ blockSums) {
  __shared__ int wsum[4];
  int lane = threadIdx.x & 63, wid = threadIdx.x >> 6;
  int tbase = blockIdx.x * SCAN_BLK + threadIdx.x * SCAN_VPT;
  int v[SCAN_VPT];
  int s = 0;
#pragma unroll
  for (int j = 0; j < SCAN_VPT; ++j) {
    int i = tbase + j;
    v[j] = (i < N_NODES) ? deg[i] : 0;
    s += v[j];
  }
  int sc = s;
#pragma unroll
  for (int o = 1; o < 64; o <<= 1) {
    int t = __shfl_up(sc, o);
    if (lane >= o) sc += t;
  }
  if (lane == 63) wsum[wid] = sc;
  __syncthreads();
  int woff = 0;
  for (int w = 0; w < wid; ++w) woff += wsum[w];
  int run = woff + sc - s;
#pragma unroll
  for (int j = 0; j < SCAN_VPT; ++j) {
    run += v[j];
    int i = tbase + j;
    if (i < N_NODES) incl[i] = run;
  }
  if (threadIdx.x == 255)
    blockSums[blockIdx.x] = woff + sc;
}

// scan_add with spine folded in: each block computes its scan-block offset by
// wave-reducing the 49 raw block sums (SCAN_NB <= 64).
__global__ __launch_bounds__(256) void scan_add_kernel(
    const int* __restrict__ deg, const int* __restrict__ incl,
    const int* __restrict__ bsums,
    int* __restrict__ rowptr, int* __restrict__ pos) {
  __shared__ int offSh;
  int sb = blockIdx.x >> 2;   // 256-node block -> 1024-node scan block
  if (threadIdx.x < 64) {
    int v = (threadIdx.x < sb) ? bsums[threadIdx.x] : 0;
#pragma unroll
    for (int o = 32; o > 0; o >>= 1) v += __shfl_down(v, o);
    if (threadIdx.x == 0) offSh = v;
  }
  __syncthreads();
  int i = blockIdx.x * 256 + threadIdx.x;
  if (i >= N_NODES) return;
  int ic = incl[i] + offSh;
  rowptr[i + 1] = ic;
  pos[i] = ic - deg[i];
  if (i == 0) rowptr[0] = 0;
}

__global__ __launch_bounds__(256) void scatter_kernel(
    const int* __restrict__ src, const int* __restrict__ dst,
    int* __restrict__ pos, int* __restrict__ srcS) {
  int i = blockIdx.x * 256 + threadIdx.x;
  if (i >= E_TOT) return;
  int s, d;
  if (i < N_EDGES) { s = src[i]; d = dst[i]; } else { s = d = i - N_EDGES; }
  int j = atomicAdd(&pos[d], 1);
  srcS[j] = s;
}

// ---------------- fused relevance + bf16 convert: ONE WAVE PER NODE ----------------
__global__ __launch_bounds__(256) void rel_conv_kernel(
    const float* __restrict__ x, const float* __restrict__ claim,
    const int* __restrict__ nb, short* __restrict__ Abf,
    float* __restrict__ alphas, float* __restrict__ alphad,
    float* __restrict__ bnsums, float* __restrict__ bnsq) {
  int wid = threadIdx.x >> 6, lane = threadIdx.x & 63;
  int n = blockIdx.x * 4 + wid;     // N_NODES % 4 == 0
  if (blockIdx.x == 0) { bnsums[threadIdx.x] = 0.f; bnsq[threadIdx.x] = 0.f; }
  if (n >= N_NODES) return;
  if (lane == 0) { alphas[n] = 0.f; alphad[n] = 0.f; }
  int g = nb[n];
  const f32x4* xr = (const f32x4*)(x + (size_t)n * D_IN);
  const f32x4* cr = (const f32x4*)(claim + (size_t)g * D_IN);
  f32x4 xv[3];
  float dot = 0.f, nx = 0.f, nc = 0.f;
#pragma unroll
  for (int j = 0; j < 3; ++j) {
    xv[j] = xr[lane + j * 64];
    f32x4 cv = cr[lane + j * 64];
#pragma unroll
    for (int k = 0; k < 4; ++k) {
      dot += xv[j][k] * cv[k];
      nx  += xv[j][k] * xv[j][k];
      nc  += cv[k] * cv[k];
    }
  }
#pragma unroll
  for (int o = 32; o > 0; o >>= 1) {
    dot += __shfl_xor(dot, o);
    nx  += __shfl_xor(nx, o);
    nc  += __shfl_xor(nc, o);
  }
  float rel = dot / fmaxf(sqrtf(nx) * sqrtf(nc), 1e-8f);
  short4v* ab = (short4v*)(Abf + (size_t)n * D_IN);
#pragma unroll
  for (int j = 0; j < 3; ++j) {
    short4v o4;
#pragma unroll
    for (int k = 0; k < 4; ++k) o4[k] = f2bs(xv[j][k] * rel);
    ab[lane + j * 64] = o4;
  }
}

// ---------------- BN finalize+scale/shift+ReLU+bf16 (layer-2 A); zeroes alpha + pooled ----------------
__global__ __launch_bounds__(256) void bn_conv_kernel(
    const float* __restrict__ agg, const float* __restrict__ sums,
    const float* __restrict__ sumsq, const float* __restrict__ gamma,
    const float* __restrict__ beta, short* __restrict__ A2,
    float* __restrict__ alphas, float* __restrict__ alphad,
    float* __restrict__ pooled) {
  int i = blockIdx.x * 256 + threadIdx.x;   // vec-4 index
  if ((i & 63) == 0) { int n = i >> 6; alphas[n] = 0.f; alphad[n] = 0.f; }
  if (i < N_GRAPHS * D_HID) pooled[i] = 0.f;
  f32x4 v = ((const f32x4*)agg)[i];
  int col = (i << 2) & (D_HID - 1);
  short4v o;
#pragma unroll
  for (int j = 0; j < 4; ++j) {
    float mu  = sums[col + j] * (1.f / N_NODES);
    float var = fmaxf(sumsq[col + j] * (1.f / N_NODES) - mu * mu, 0.f);
    float sc  = gamma[col + j] * rsqrtf(var + 1e-5f);
    float sh  = beta[col + j] - mu * sc;
    float t = fmaxf(v[j] * sc + sh, 0.f);
    o[j] = f2bs(t);
  }
  ((short4v*)A2)[i] = o;
}

// ---------------- MFMA GEMM (bf16 in/out): C[M,256] = A[M,K] @ B[K,256] ----------------
// 128x128 tile per block, 4 waves (2x2), per-wave 64x64 = 4x4 MFMA tiles, BK=32.
// LDS fragment-major layout (R4-verified): staging decode quad-fastest so each
// 4-lane group fetches a contiguous 64B row chunk (coalesced); ds_read offsets
// l16*32+quadL*8.
// XCD PAIRING SWIZZLE: the two n-halves of each m-tile share A rows. Map pair
// p, half q -> hw bid (p/8)*16 + q*8 + p%8 so both halves land on the SAME XCD
// => second A read is an L2 hit instead of a second HBM fetch.
// Fused epilogue: alpha_s/alpha_d = acc . a (cross-lane reduce + atomicAdd), C bf16.
#define GEMM_BK 32
__global__ __launch_bounds__(256) void mfma_gemm_bf16_kernel(
    const short* __restrict__ Abf, const short* __restrict__ BT,
    const float* __restrict__ aS, const float* __restrict__ aD,
    float* __restrict__ alphaS, float* __restrict__ alphaD,
    bf16* __restrict__ C, int M, int K) {
  __shared__ short As[4096];   // 8 m-tiles * 512 shorts
  __shared__ short Bs[4096];   // 8 n-tiles * 512 shorts
  int tid = threadIdx.x;
  int wave = tid >> 6, lane = tid & 63;
  int l16 = lane & 15, quadL = lane >> 4;
  int wr = wave >> 1, wc = wave & 1;
  // XCD pairing decode
  int B = blockIdx.x;
  int p = (B >> 4) * 8 + (B & 7);      // m-tile index
  int q = (B >> 3) & 1;                // n-half
  int mTiles = (M + 127) >> 7;
  if (p >= mTiles) return;
  int mBase = p * 128;
  int nBase = q * 128;

  const short* gA[2];
  const short* gB[2];
  int ldsOff[2];
#pragma unroll
  for (int r = 0; r < 2; ++r) {
    int slot = r * 256 + tid;              // 16B granule index 0..511 (linear dest)
    int mt = slot >> 6, m16 = (slot >> 2) & 15, quad = slot & 3;  // quad fastest: coalesced
    int rowA = min(mBase + mt * 16 + m16, M - 1);   // clamp OOB rows (outputs masked)
    gA[r] = Abf + (size_t)rowA * K + quad * 8;
    gB[r] = BT + (size_t)(nBase + mt * 16 + m16) * K + quad * 8;
    ldsOff[r] = (r * 256 + wave * 64) * 8; // wave-uniform LDS base (shorts)
  }
  int aOff[4], bOff[4];
#pragma unroll
  for (int i = 0; i < 4; ++i) {
    aOff[i] = (wr * 4 + i) * 512 + l16 * 32 + quadL * 8;
    bOff[i] = (wc * 4 + i) * 512 + l16 * 32 + quadL * 8;
  }

  f32x4 acc[4][4] = {};

  for (int k0 = 0; k0 < K; k0 += GEMM_BK) {
#pragma unroll
    for (int r = 0; r < 2; ++r) {
      gload_lds16(gA[r] + k0, As + ldsOff[r]);
      gload_lds16(gB[r] + k0, Bs + ldsOff[r]);
    }
    __syncthreads();   // drains vmcnt before barrier
    short8 af[4], bfv[4];
#pragma unroll
    for (int i = 0; i < 4; ++i) af[i] = *(const short8*)(As + aOff[i]);
#pragma unroll
    for (int j = 0; j < 4; ++j) bfv[j] = *(const short8*)(Bs + bOff[j]);
#pragma unroll
    for (int i = 0; i < 4; ++i)
#pragma unroll
      for (int j = 0; j < 4; ++j)
        acc[i][j] = __builtin_amdgcn_mfma_f32_16x16x32_bf16(af[i], bfv[j], acc[i][j], 0, 0, 0);
    __syncthreads();
  }

  // ---- epilogue: fused alpha + bf16 store ----
  float asv[4], adv[4];
#pragma unroll
  for (int j = 0; j < 4; ++j) {
    int col = nBase + (wc * 4 + j) * 16 + l16;
    asv[j] = aS[col]; adv[j] = aD[col];
  }
#pragma unroll
  for (int i = 0; i < 4; ++i) {
    int m0 = mBase + (wr * 4 + i) * 16 + quadL * 4;
#pragma unroll
    for (int r = 0; r < 4; ++r) {
      int m = m0 + r;
      float ss = acc[i][0][r] * asv[0] + acc[i][1][r] * asv[1] +
                 acc[i][2][r] * asv[2] + acc[i][3][r] * asv[3];
      float dd = acc[i][0][r] * adv[0] + acc[i][1][r] * adv[1] +
                 acc[i][2][r] * adv[2] + acc[i][3][r] * adv[3];
#pragma unroll
      for (int o = 1; o < 16; o <<= 1) {
        ss += __shfl_xor(ss, o);
        dd += __shfl_xor(dd, o);
      }
      if (m < M) {
        if (l16 == 0) { atomicAdd(&alphaS[m], ss); atomicAdd(&alphaD[m], dd); }
#pragma unroll
        for (int j = 0; j < 4; ++j)
          C[(size_t)m * D_HID + nBase + (wc * 4 + j) * 16 + l16] =
              __float2bfloat16(acc[i][j][r]);
      }
    }
  }
}

// ---------------- fused GAT softmax + aggregate: one wave per dst node ----------------
// Single gather pass; chunk-0 edges cached in registers, exp weight shfl'd.
// (R6's FUSE_POOL variant reverted: 12.8M atomicAdds onto 32K addresses was
// ~390-deep serialization per address -> 255us latency-bound dispatch.)
__global__ __launch_bounds__(256) void gat_agg_kernel(
    const int* __restrict__ rowptr, const int* __restrict__ srcS,
    const float* __restrict__ as_, const float* __restrict__ ad_,
    const bf16* __restrict__ h, float* __restrict__ agg) {
  int wid = threadIdx.x >> 6, lane = threadIdx.x & 63;
  int n = blockIdx.x * 4 + wid;
  if (n >= N_NODES) return;
  int start = rowptr[n], end = rowptr[n + 1];
  int deg = end - start;
  float adn = ad_[n];
  // cache chunk 0 in registers
  int sidx = 0;
  float e0 = -1e30f;
  if (lane < deg) {
    sidx = srcS[start + lane];
    float e = as_[sidx] + adn;
    e0 = e > 0.f ? e : 0.2f * e;
  }
  float m = e0;
  for (int j0 = start + 64; j0 < end; j0 += 64) {   // rare (deg > 64)
    int j = j0 + lane;
    if (j < end) {
      float e = as_[srcS[j]] + adn;
      e = e > 0.f ? e : 0.2f * e;
      m = fmaxf(m, e);
    }
  }
#pragma unroll
  for (int o = 32; o > 0; o >>= 1) m = fmaxf(m, __shfl_xor(m, o));
  float pw = (lane < deg) ? __expf(e0 - m) : 0.f;   // per-lane weight, shfl'd later
  float ssum = pw;
  for (int j0 = start + 64; j0 < end; j0 += 64) {
    int j = j0 + lane;
    if (j < end) {
      float e = as_[srcS[j]] + adn;
      e = e > 0.f ? e : 0.2f * e;
      ssum += __expf(e - m);
    }
  }
#pragma unroll
  for (int o = 32; o > 0; o >>= 1) ssum += __shfl_xor(ssum, o);
  float a0 = 0.f, a1 = 0.f, a2 = 0.f, a3 = 0.f;
  const unsigned short* hp = (const unsigned short*)h;
  int c0 = min(deg, 64);
  for (int t = 0; t < c0; ++t) {
    int s = __shfl(sidx, t);
    float w = __shfl(pw, t);
    const ushort4 hv = *(const ushort4*)(hp + (size_t)s * D_HID + lane * 4);
    a0 += us2f(hv.x) * w;
    a1 += us2f(hv.y) * w;
    a2 += us2f(hv.z) * w;
    a3 += us2f(hv.w) * w;
  }
  for (int j = start + 64; j < end; ++j) {   // rare tail
    int s = srcS[j];
    float e = as_[s] + adn;
    e = e > 0.f ? e : 0.2f * e;
    float w = __expf(e - m);
    const ushort4 hv = *(const ushort4*)(hp + (size_t)s * D_HID + lane * 4);
    a0 += us2f(hv.x) * w;
    a1 += us2f(hv.y) * w;
    a2 += us2f(hv.z) * w;
    a3 += us2f(hv.w) * w;
  }
  float inv = 1.f / ssum;
  float4 o4 = {a0 * inv, a1 * inv, a2 * inv, a3 * inv};
  *(float4*)(agg + (size_t)n * D_HID + lane * 4) = o4;
}

// ---------------- batch norm stats (accumulators pre-zeroed by rel_conv) ----------------
__global__ __launch_bounds__(256) void bn_stats_kernel(
    const float* __restrict__ h, float* __restrict__ sums, float* __restrict__ sumsq) {
  int col = threadIdx.x;
  float s = 0.f, q = 0.f;
  for (int r = blockIdx.x; r < N_NODES; r += gridDim.x) {
    float v = h[(size_t)r * D_HID + col];
    s += v; q += v * v;
  }
  atomicAdd(&sums[col], s);
  atomicAdd(&sumsq[col], q);
}

// ---------------- mean pool (node_batch sorted) + b2 + relu ----------------
__global__ __launch_bounds__(256) void pool_kernel(
    const float* __restrict__ h, const float* __restrict__ bias2,
    const int* __restrict__ nb, float* __restrict__ pooled) {
  int col = threadIdx.x;
  float bias = bias2[col];
  int chunk = (N_NODES + gridDim.x - 1) / gridDim.x;
  int r0 = blockIdx.x * chunk;
  int r1 = min(N_NODES, r0 + chunk);
  float acc = 0.f; int cur = -1;
  for (int r = r0; r < r1; ++r) {
    int g = nb[r];
    if (g != cur) {
      if (cur >= 0) atomicAdd(&pooled[(size_t)cur * D_HID + col], acc);
      acc = 0.f; cur = g;
    }
    acc += fmaxf(h[(size_t)r * D_HID + col] + bias, 0.f);
  }
  if (cur >= 0) atomicAdd(&pooled[(size_t)cur * D_HID + col], acc);
}

// ---------------- classifier; per-graph count via binary search on sorted nb ----------------
__global__ __launch_bounds__(256) void clf_kernel(
    const float* __restrict__ pooled, const int* __restrict__ nb,
    const float* __restrict__ claim, const float* __restrict__ clfW,
    const float* __restrict__ clfb, float* __restrict__ out) {
  __shared__ float buf[4];
  __shared__ int cntSh;
  int g = blockIdx.x;
  if (threadIdx.x == 0) {
    int lo = 0, hi = N_NODES;
    while (lo < hi) { int mid = (lo + hi) >> 1; if (nb[mid] < g) lo = mid + 1; else hi = mid; }
    int lb = lo; hi = N_NODES;
    while (lo < hi) { int mid = (lo + hi) >> 1; if (nb[mid] <= g) lo = mid + 1; else hi = mid; }
    cntSh = lo - lb;
  }
  __syncthreads();
  float inv = 1.f / fmaxf((float)cntSh, 1.f);
  float p = 0.f;
  for (int d = threadIdx.x; d < (D_HID + D_IN); d += 256) {
    float w = clfW[d];
    float v = (d < D_HID) ? pooled[(size_t)g * D_HID + d] * inv
                          : claim[(size_t)g * D_IN + (d - D_HID)];
    p += v * w;
  }
  p = blockReduce256(p, buf);
  if (threadIdx.x == 0) out[g] = p + clfb[0];
}

extern "C" void kernel_launch(void* const* d_in, const int* in_sizes, int n_in,
                              void* d_out, int out_size, void* d_ws, size_t ws_size,
                              hipStream_t stream) {
  const float* claim = (const float*)d_in[0];
  const float* x     = (const float*)d_in[1];
  const void*  edge  = d_in[2];
  const void*  nbin  = d_in[3];
  const float* W1    = (const float*)d_in[4];
  const float* as1   = (const float*)d_in[5];
  const float* ad1   = (const float*)d_in[6];
  // d_in[7] = b1: cancels in BatchNorm
  const float* W2    = (const float*)d_in[8];
  const float* as2   = (const float*)d_in[9];
  const float* ad2   = (const float*)d_in[10];
  const float* b2v   = (const float*)d_in[11];
  const float* gamma = (const float*)d_in[12];
  const float* beta  = (const float*)d_in[13];
  const float* clfW  = (const float*)d_in[14];
  const float* clfb  = (const float*)d_in[15];
  float* out = (float*)d_out;

  char* wsb = (char*)d_ws;
  size_t off = 0;
  auto alloc = [&](size_t bytes) -> char* {
    char* p = wsb + off;
    off = (off + bytes + 255) & ~(size_t)255;
    return p;
  };
  int*   flagNZ = (int*)alloc(sizeof(int));
  int*   src32  = (int*)alloc((size_t)N_EDGES * sizeof(int));
  int*   dst32  = (int*)alloc((size_t)N_EDGES * sizeof(int));
  int*   nb32   = (int*)alloc((size_t)N_NODES * sizeof(int));
  int*   deg    = (int*)alloc((size_t)N_NODES * sizeof(int));
  int*   rowptr = (int*)alloc((size_t)(N_NODES + 1) * sizeof(int));
  int*   pos    = (int*)alloc((size_t)N_NODES * sizeof(int));
  int*   incl   = (int*)alloc((size_t)N_NODES * sizeof(int));
  int*   bsums  = (int*)alloc((size_t)SCAN_NB * sizeof(int));
  int*   srcS   = (int*)alloc((size_t)E_TOT * sizeof(int));
  short* W1T    = (short*)alloc((size_t)D_IN * D_HID * sizeof(short));
  short* W2T    = (short*)alloc((size_t)D_HID * D_HID * sizeof(short));
  float* alphas = (float*)alloc((size_t)N_NODES * sizeof(float));
  float* alphad = (float*)alloc((size_t)N_NODES * sizeof(float));
  float* bnsums = (float*)alloc(D_HID * sizeof(float));
  float* bnsq   = (float*)alloc(D_HID * sizeof(float));
  float* pooled = (float*)alloc((size_t)N_GRAPHS * D_HID * sizeof(float));
  float* agg    = (float*)alloc((size_t)N_NODES * D_HID * sizeof(float));
  bf16*  h      = (bf16*) alloc((size_t)N_NODES * D_HID * sizeof(bf16));
  short* Abf    = (short*)alloc((size_t)N_NODES * D_IN * sizeof(short));
  short* A2     = Abf;   // layer-2 bf16 A reuses Abf

  // ---- index normalization + CSR build (no memsets: kernels self-initialize) ----
  detect_idx_kernel<<<1, 256, 0, stream>>>((const int*)edge, flagNZ);
  normalize_idx_kernel<<<(N_EDGES + N_NODES + 255) / 256, 256, 0, stream>>>(
      edge, nbin, flagNZ, src32, dst32, nb32, deg, W1, W2, W1T, W2T);
  int egrid = (E_TOT + 255) / 256;
  hist_kernel<<<egrid, 256, 0, stream>>>(dst32, deg);
  scan_local_kernel<<<SCAN_NB, 256, 0, stream>>>(deg, incl, bsums);
  scan_add_kernel<<<(N_NODES + 255) / 256, 256, 0, stream>>>(deg, incl, bsums, rowptr, pos);
  scatter_kernel<<<egrid, 256, 0, stream>>>(src32, dst32, pos, srcS);

  // XCD-paired GEMM grid: ceil(mTiles/8)*16 hw blocks
  int mTiles = (N_NODES + 127) / 128;             // 391
  int gemmGrid = ((mTiles + 7) / 8) * 16;         // 784

  // ---- layer 1 ----
  rel_conv_kernel<<<N_NODES / 4, 256, 0, stream>>>(
      x, claim, nb32, Abf, alphas, alphad, bnsums, bnsq);
  mfma_gemm_bf16_kernel<<<gemmGrid, 256, 0, stream>>>(
      Abf, W1T, as1, ad1, alphas, alphad, h, N_NODES, D_IN);
  gat_agg_kernel<<<N_NODES / 4, 256, 0, stream>>>(rowptr, srcS, alphas, alphad, h, agg);

  bn_stats_kernel<<<256, 256, 0, stream>>>(agg, bnsums, bnsq);

  // ---- layer 2 (BN finalize + scale/shift + ReLU folded into bf16 conversion) ----
  bn_conv_kernel<<<(N_NODES * D_HID / 4 + 255) / 256, 256, 0, stream>>>(
      agg, bnsums, bnsq, gamma, beta, A2, alphas, alphad, pooled);
  mfma_gemm_bf16_kernel<<<gemmGrid, 256, 0, stream>>>(
      A2, W2T, as2, ad2, alphas, alphad, h, N_NODES, D_HID);
  gat_agg_kernel<<<N_NODES / 4, 256, 0, stream>>>(rowptr, srcS, alphas, alphad, h, agg);

  // ---- pool + classifier ----
  pool_kernel<<<256, 256, 0, stream>>>(agg, b2v, nb32, pooled);
  clf_kernel<<<N_GRAPHS, 256, 0, stream>>>(pooled, nb32, claim, clfW, clfb, out);
}